// Round 1
// baseline (407.689 us; speedup 1.0000x reference)
//
#include <hip/hip_runtime.h>
#include <math.h>

#define CC 64
#define HH 80
#define WW 160
#define BB 3
#define LL 4
#define HWp (HH * WW)
#define EPSf 1e-5f
#define NEGf -1e30f

// ---------- helpers ----------

__device__ __forceinline__ float tapf(const float* __restrict__ f, int xi, int yi) {
    bool inb = (xi >= 0) & (xi < WW) & (yi >= 0) & (yi < HH);
    int xc = min(max(xi, 0), WW - 1);
    int yc = min(max(yi, 0), HH - 1);
    float v = f[yc * WW + xc];
    return inb ? v : 0.0f;
}

__device__ __forceinline__ float bilin(const float* __restrict__ f, float px, float py) {
    float x0f = floorf(px), y0f = floorf(py);
    float wx = px - x0f, wy = py - y0f;
    int x0 = (int)x0f, y0 = (int)y0f;
    return tapf(f, x0,     y0    ) * (1.f - wx) * (1.f - wy)
         + tapf(f, x0 + 1, y0    ) * wx         * (1.f - wy)
         + tapf(f, x0,     y0 + 1) * (1.f - wx) * wy
         + tapf(f, x0 + 1, y0 + 1) * wx         * wy;
}

__device__ __forceinline__ void src_xy(const float* __restrict__ th, int pix,
                                       float& px, float& py) {
    int w = pix % WW, h = pix / WW;
    float gx = -1.f + 2.f * (float)w / (float)(WW - 1);
    float gy = -1.f + 2.f * (float)h / (float)(HH - 1);
    float sx = th[0] * gx + th[1] * gy + th[2];
    float sy = th[3] * gx + th[4] * gy + th[5];
    px = (sx + 1.f) * (float)(WW - 1) * 0.5f;
    py = (sy + 1.f) * (float)(HH - 1) * 0.5f;
}

// ---------- kernel 1: warp node features (i = 0 slice only) ----------
// nbr[((b*L + j)*C + c)*HW + pix]

__global__ __launch_bounds__(256) void k_warp(
    const float* __restrict__ x, const int* __restrict__ rec,
    const float* __restrict__ ptm, float* __restrict__ nbr)
{
    int idx = blockIdx.x * blockDim.x + threadIdx.x;
    if (idx >= BB * LL * CC * HWp) return;
    int pix = idx % HWp;
    int t   = idx / HWp;
    int c   = t % CC;
    int bj  = t / CC;
    int j = bj % LL, b = bj / LL;
    int r0 = rec[0], r1 = rec[1], r2 = rec[2];
    int rb = (b == 0) ? r0 : ((b == 1) ? r1 : r2);
    if (j >= rb) { nbr[idx] = 0.f; return; }
    int off = (b >= 1 ? r0 : 0) + (b >= 2 ? r1 : 0);
    const float* feat = x + ((size_t)(off + j) * CC + c) * HWp;
    const float* th = ptm + (size_t)(b * LL + j) * LL * 6;  // ptm[b][j][0]
    float px, py;
    src_xy(th, pix, px, py);
    nbr[idx] = bilin(feat, px, py);
}

// ---------- kernel 2: per-(b,j,pix) score MLP + warped mask ----------

__global__ __launch_bounds__(256) void k_score(
    const float* __restrict__ x, const float* __restrict__ mask,
    const int* __restrict__ rec, const float* __restrict__ ptm,
    const float* __restrict__ nbr,
    const float* __restrict__ w1, const float* __restrict__ cb1,
    const float* __restrict__ g1, const float* __restrict__ be1,
    const float* __restrict__ rm1, const float* __restrict__ rv1,
    const float* __restrict__ w2, const float* __restrict__ cb2,
    const float* __restrict__ g2, const float* __restrict__ be2,
    const float* __restrict__ rm2, const float* __restrict__ rv2,
    const float* __restrict__ w3, const float* __restrict__ cb3,
    const float* __restrict__ g3, const float* __restrict__ be3,
    const float* __restrict__ rm3, const float* __restrict__ rv3,
    const float* __restrict__ w4, const float* __restrict__ cb4,
    float* __restrict__ s_out, float* __restrict__ com_out)
{
    int idx = blockIdx.x * blockDim.x + threadIdx.x;
    if (idx >= BB * LL * HWp) return;
    int pix = idx % HWp;
    int bj  = idx / HWp;
    int j = bj % LL, b = bj / LL;
    int r0 = rec[0], r1 = rec[1], r2 = rec[2];
    int rb = (b == 0) ? r0 : ((b == 1) ? r1 : r2);
    if (j >= rb) { s_out[idx] = NEGf; com_out[idx] = 0.f; return; }

    const float* th = ptm + (size_t)(b * LL + j) * LL * 6;
    float px, py;
    src_xy(th, pix, px, py);
    float wm = bilin(mask + (size_t)bj * HWp, px, py);  // valid[b][j] == 1 here

    int off = (b >= 1 ? r0 : 0) + (b >= 2 ? r1 : 0);

    // layer 1: z = [nbr(64) ; ego(64)] -> 128
    float h1[128];
    #pragma unroll
    for (int o = 0; o < 128; ++o) h1[o] = 0.f;

    const float* nb = nbr + (size_t)bj * CC * HWp + pix;
    #pragma unroll 1
    for (int c = 0; c < CC; ++c) {
        float zc = nb[c * HWp];
        #pragma unroll
        for (int o = 0; o < 128; ++o) h1[o] = fmaf(zc, w1[c * 128 + o], h1[o]);
    }
    const float* eg = x + (size_t)off * CC * HWp + pix;  // node[b][0] (rec[b] >= 1)
    #pragma unroll 1
    for (int c = 0; c < CC; ++c) {
        float zc = eg[c * HWp];
        #pragma unroll
        for (int o = 0; o < 128; ++o) h1[o] = fmaf(zc, w1[(CC + c) * 128 + o], h1[o]);
    }
    #pragma unroll
    for (int o = 0; o < 128; ++o) {
        float k = g1[o] * rsqrtf(rv1[o] + EPSf);
        h1[o] = fmaxf(fmaf(h1[o] + cb1[o] - rm1[o], k, be1[o]), 0.f);
    }

    // layer 2: 128 -> 32
    float h2[32];
    #pragma unroll
    for (int o = 0; o < 32; ++o) h2[o] = 0.f;
    #pragma unroll
    for (int c = 0; c < 128; ++c) {
        #pragma unroll
        for (int o = 0; o < 32; ++o) h2[o] = fmaf(h1[c], w2[c * 32 + o], h2[o]);
    }
    #pragma unroll
    for (int o = 0; o < 32; ++o) {
        float k = g2[o] * rsqrtf(rv2[o] + EPSf);
        h2[o] = fmaxf(fmaf(h2[o] + cb2[o] - rm2[o], k, be2[o]), 0.f);
    }

    // layer 3: 32 -> 8
    float h3[8];
    #pragma unroll
    for (int o = 0; o < 8; ++o) h3[o] = 0.f;
    #pragma unroll
    for (int c = 0; c < 32; ++c) {
        #pragma unroll
        for (int o = 0; o < 8; ++o) h3[o] = fmaf(h2[c], w3[c * 8 + o], h3[o]);
    }
    #pragma unroll
    for (int o = 0; o < 8; ++o) {
        float k = g3[o] * rsqrtf(rv3[o] + EPSf);
        h3[o] = fmaxf(fmaf(h3[o] + cb3[o] - rm3[o], k, be3[o]), 0.f);
    }

    // layer 4: 8 -> 1
    float s = cb4[0];
    #pragma unroll
    for (int c = 0; c < 8; ++c) s = fmaf(h3[c], w4[c], s);
    s = fmaxf(s, 0.f);

    s_out[idx]   = (wm == 0.f) ? NEGf : s;
    com_out[idx] = wm;
}

// ---------- kernel 3: softmax over j + weighted sum + output MLP ----------

__global__ __launch_bounds__(256) void k_fuse(
    const float* __restrict__ nbr, const float* __restrict__ s_in,
    const float* __restrict__ com_in, const float* __restrict__ mlp_w,
    const float* __restrict__ mlp_b, float* __restrict__ out)
{
    int idx = blockIdx.x * blockDim.x + threadIdx.x;
    if (idx >= BB * HWp) return;
    int pix = idx % HWp, b = idx / HWp;

    float sj[LL], cj[LL];
    #pragma unroll
    for (int j = 0; j < LL; ++j) {
        sj[j] = s_in[(size_t)(b * LL + j) * HWp + pix];
        cj[j] = com_in[(size_t)(b * LL + j) * HWp + pix];
    }
    float m = fmaxf(fmaxf(sj[0], sj[1]), fmaxf(sj[2], sj[3]));
    float e[LL], sum = 0.f;
    #pragma unroll
    for (int j = 0; j < LL; ++j) { e[j] = __expf(sj[j] - m); sum += e[j]; }
    float inv = 1.f / sum;
    float wgt[LL];
    #pragma unroll
    for (int j = 0; j < LL; ++j) wgt[j] = e[j] * inv * cj[j];

    float upd[CC];
    #pragma unroll
    for (int c = 0; c < CC; ++c) upd[c] = 0.f;
    #pragma unroll
    for (int j = 0; j < LL; ++j) {
        const float* nb = nbr + (size_t)(b * LL + j) * CC * HWp + pix;
        float wj = wgt[j];
        #pragma unroll
        for (int c = 0; c < CC; ++c) upd[c] = fmaf(wj, nb[c * HWp], upd[c]);
    }

    // out[b][d] = sum_c upd[c] * mlp_w[c][d] + mlp_b[d]
    #pragma unroll 1
    for (int d = 0; d < CC; ++d) {
        float a0 = 0.f, a1 = 0.f, a2 = 0.f, a3 = 0.f;
        #pragma unroll
        for (int c = 0; c < CC; c += 4) {
            a0 = fmaf(upd[c + 0], mlp_w[(c + 0) * CC + d], a0);
            a1 = fmaf(upd[c + 1], mlp_w[(c + 1) * CC + d], a1);
            a2 = fmaf(upd[c + 2], mlp_w[(c + 2) * CC + d], a2);
            a3 = fmaf(upd[c + 3], mlp_w[(c + 3) * CC + d], a3);
        }
        out[(size_t)(b * CC + d) * HWp + pix] = (a0 + a1) + (a2 + a3) + mlp_b[d];
    }
}

// ---------- launch ----------

extern "C" void kernel_launch(void* const* d_in, const int* in_sizes, int n_in,
                              void* d_out, int out_size, void* d_ws, size_t ws_size,
                              hipStream_t stream)
{
    const float* x    = (const float*)d_in[0];
    const float* mask = (const float*)d_in[1];
    const int*   rec  = (const int*)  d_in[2];
    const float* ptm  = (const float*)d_in[3];
    const float* w1   = (const float*)d_in[4];
    const float* cb1  = (const float*)d_in[5];
    const float* g1   = (const float*)d_in[6];
    const float* be1  = (const float*)d_in[7];
    const float* rm1  = (const float*)d_in[8];
    const float* rv1  = (const float*)d_in[9];
    const float* w2   = (const float*)d_in[10];
    const float* cb2  = (const float*)d_in[11];
    const float* g2   = (const float*)d_in[12];
    const float* be2  = (const float*)d_in[13];
    const float* rm2  = (const float*)d_in[14];
    const float* rv2  = (const float*)d_in[15];
    const float* w3   = (const float*)d_in[16];
    const float* cb3  = (const float*)d_in[17];
    const float* g3   = (const float*)d_in[18];
    const float* be3  = (const float*)d_in[19];
    const float* rm3  = (const float*)d_in[20];
    const float* rv3  = (const float*)d_in[21];
    const float* w4   = (const float*)d_in[22];
    const float* cb4  = (const float*)d_in[23];
    const float* mlpw = (const float*)d_in[24];
    const float* mlpb = (const float*)d_in[25];
    float* out = (float*)d_out;

    float* nbr_ws = (float*)d_ws;
    float* s_ws   = nbr_ws + (size_t)BB * LL * CC * HWp;
    float* com_ws = s_ws   + (size_t)BB * LL * HWp;

    int n1 = BB * LL * CC * HWp;
    k_warp<<<dim3((n1 + 255) / 256), dim3(256), 0, stream>>>(x, rec, ptm, nbr_ws);

    int n2 = BB * LL * HWp;
    k_score<<<dim3((n2 + 255) / 256), dim3(256), 0, stream>>>(
        x, mask, rec, ptm, nbr_ws,
        w1, cb1, g1, be1, rm1, rv1,
        w2, cb2, g2, be2, rm2, rv2,
        w3, cb3, g3, be3, rm3, rv3,
        w4, cb4, s_ws, com_ws);

    int n3 = BB * HWp;
    k_fuse<<<dim3((n3 + 255) / 256), dim3(256), 0, stream>>>(
        nbr_ws, s_ws, com_ws, mlpw, mlpb, out);
}

// Round 2
// 181.180 us; speedup vs baseline: 2.2502x; 2.2502x over previous
//
#include <hip/hip_runtime.h>
#include <math.h>

#define CC 64
#define HH 80
#define WW 160
#define BB 3
#define LL 4
#define HW (HH * WW)          // 12800
#define EPSf 1e-5f
#define NEGf -1e30f

typedef __attribute__((ext_vector_type(8))) short bf16x8;
typedef __attribute__((ext_vector_type(4))) float f32x4;

__device__ __forceinline__ unsigned short f2bf(float f) {
    unsigned int u = __float_as_uint(f);
    u = u + 0x7fffu + ((u >> 16) & 1u);      // RNE
    return (unsigned short)(u >> 16);
}
__device__ __forceinline__ float b2f(unsigned short h) {
    return __uint_as_float(((unsigned int)h) << 16);
}

__device__ __forceinline__ void src_xy(const float* __restrict__ th, int pix,
                                       float& px, float& py) {
    int w = pix % WW, h = pix / WW;
    float gx = -1.f + 2.f * (float)w / (float)(WW - 1);
    float gy = -1.f + 2.f * (float)h / (float)(HH - 1);
    float sx = th[0] * gx + th[1] * gy + th[2];
    float sy = th[3] * gx + th[4] * gy + th[5];
    px = (sx + 1.f) * (float)(WW - 1) * 0.5f;
    py = (sy + 1.f) * (float)(HH - 1) * 0.5f;
}

// ---------------- prep: weight transpose+bf16, BN folding ----------------

__global__ __launch_bounds__(256) void k_prep(
    const float* __restrict__ w1, const float* __restrict__ w2,
    const float* __restrict__ cb1, const float* __restrict__ g1,
    const float* __restrict__ be1, const float* __restrict__ rm1, const float* __restrict__ rv1,
    const float* __restrict__ cb2, const float* __restrict__ g2,
    const float* __restrict__ be2, const float* __restrict__ rm2, const float* __restrict__ rv2,
    const float* __restrict__ cb3, const float* __restrict__ g3,
    const float* __restrict__ be3, const float* __restrict__ rm3, const float* __restrict__ rv3,
    unsigned short* __restrict__ w1T, unsigned short* __restrict__ w2T,
    float* __restrict__ kk1, float* __restrict__ bb1,
    float* __restrict__ kk2, float* __restrict__ bb2,
    float* __restrict__ kk3, float* __restrict__ bb3)
{
    int idx = blockIdx.x * 256 + threadIdx.x;
    if (idx < 16384) {                       // w1T[o][c] = w1[c][o]
        int o = idx >> 7, c = idx & 127;
        w1T[idx] = f2bf(w1[c * 128 + o]);
    } else if (idx < 20480) {                // w2T[o2][o] = w2[o][o2]
        int i = idx - 16384;
        int o2 = i >> 7, o = i & 127;
        w2T[i] = f2bf(w2[o * 32 + o2]);
    } else if (idx < 20608) {
        int o = idx - 20480;
        float k = g1[o] * rsqrtf(rv1[o] + EPSf);
        kk1[o] = k; bb1[o] = fmaf(cb1[o] - rm1[o], k, be1[o]);
    } else if (idx < 20640) {
        int o = idx - 20608;
        float k = g2[o] * rsqrtf(rv2[o] + EPSf);
        kk2[o] = k; bb2[o] = fmaf(cb2[o] - rm2[o], k, be2[o]);
    } else if (idx < 20648) {
        int o = idx - 20640;
        float k = g3[o] * rsqrtf(rv3[o] + EPSf);
        kk3[o] = k; bb3[o] = fmaf(cb3[o] - rm3[o], k, be3[o]);
    }
}

// ---------------- warp: nbr_t[bj][pix][c] bf16, ego_t[b][pix][c] bf16, com ----------------
// grid: [0,2400) nbr tiles (12 bj x 200), [2400,3000) ego tiles (3 b x 200)

__global__ __launch_bounds__(256) void k_warp(
    const float* __restrict__ x, const float* __restrict__ mask,
    const int* __restrict__ rec, const float* __restrict__ ptm,
    unsigned short* __restrict__ nbr_t, unsigned short* __restrict__ ego_t,
    float* __restrict__ com)
{
    __shared__ unsigned short tile_s[64 * 72];
    int bid = blockIdx.x, t = threadIdx.x;
    int p = t & 63, cg = t >> 6;
    int r0 = rec[0], r1 = rec[1], r2 = rec[2];

    if (bid < 2400) {
        int bj = bid / 200, tile = bid % 200;
        int b = bj >> 2, j = bj & 3;
        int rb = (b == 0) ? r0 : ((b == 1) ? r1 : r2);
        int pix0 = tile * 64;
        if (j >= rb) {
            if (t < 64) com[(size_t)bj * HW + pix0 + t] = 0.f;
            return;
        }
        int off = (b >= 1 ? r0 : 0) + (b >= 2 ? r1 : 0);
        const float* th = ptm + ((size_t)(b * 4 + j) * 4 + 0) * 6;
        int pix = pix0 + p;
        float px, py; src_xy(th, pix, px, py);
        float x0f = floorf(px), y0f = floorf(py);
        float wx = px - x0f, wy = py - y0f;
        int x0 = (int)x0f, y0 = (int)y0f, x1 = x0 + 1, y1 = y0 + 1;
        float bx0 = (x0 >= 0 && x0 < WW) ? 1.f : 0.f;
        float bx1 = (x1 >= 0 && x1 < WW) ? 1.f : 0.f;
        float by0 = (y0 >= 0 && y0 < HH) ? 1.f : 0.f;
        float by1 = (y1 >= 0 && y1 < HH) ? 1.f : 0.f;
        int xc0 = min(max(x0, 0), WW - 1), xc1 = min(max(x1, 0), WW - 1);
        int yc0 = min(max(y0, 0), HH - 1), yc1 = min(max(y1, 0), HH - 1);
        float w00 = (1.f - wx) * (1.f - wy) * bx0 * by0;
        float w01 = wx * (1.f - wy) * bx1 * by0;
        float w10 = (1.f - wx) * wy * bx0 * by1;
        float w11 = wx * wy * bx1 * by1;
        int a00 = yc0 * WW + xc0, a01 = yc0 * WW + xc1;
        int a10 = yc1 * WW + xc0, a11 = yc1 * WW + xc1;
        const float* feat = x + (size_t)(off + j) * CC * HW;
        #pragma unroll
        for (int i = 0; i < 16; ++i) {
            int c = cg * 16 + i;
            const float* f = feat + (size_t)c * HW;
            float v = w00 * f[a00] + w01 * f[a01] + w10 * f[a10] + w11 * f[a11];
            tile_s[p * 72 + c] = f2bf(v);
        }
        if (t < 64) {
            const float* mk = mask + (size_t)(b * 4 + j) * HW;
            float wm = w00 * mk[a00] + w01 * mk[a01] + w10 * mk[a10] + w11 * mk[a11];
            com[(size_t)bj * HW + pix0 + t] = wm;
        }
        __syncthreads();
        unsigned short* dst = nbr_t + ((size_t)bj * HW + pix0) * 64;
        #pragma unroll
        for (int i = 0; i < 2; ++i) {
            int u = i * 256 + t; int pr = u >> 3, cu = u & 7;
            *(uint4*)(dst + pr * 64 + cu * 8) = *(const uint4*)&tile_s[pr * 72 + cu * 8];
        }
    } else {
        int eb = bid - 2400;
        int b = eb / 200, tile = eb % 200, pix0 = tile * 64;
        int off = (b >= 1 ? r0 : 0) + (b >= 2 ? r1 : 0);
        const float* feat = x + (size_t)off * CC * HW;
        #pragma unroll
        for (int i = 0; i < 16; ++i) {
            int c = cg * 16 + i;
            tile_s[p * 72 + c] = f2bf(feat[(size_t)c * HW + pix0 + p]);
        }
        __syncthreads();
        unsigned short* dst = ego_t + ((size_t)b * HW + pix0) * 64;
        #pragma unroll
        for (int i = 0; i < 2; ++i) {
            int u = i * 256 + t; int pr = u >> 3, cu = u & 7;
            *(uint4*)(dst + pr * 64 + cu * 8) = *(const uint4*)&tile_s[pr * 72 + cu * 8];
        }
    }
}

// ---------------- score: MFMA layers 1-2, scalar layers 3-4 ----------------
// grid: 12 bj x 100 tiles of 128 pixels; 256 threads = 4 waves, 32 pix rows/wave

__global__ __launch_bounds__(256) void k_score(
    const unsigned short* __restrict__ nbr_t, const unsigned short* __restrict__ ego_t,
    const unsigned short* __restrict__ w1T, const unsigned short* __restrict__ w2T,
    const float* __restrict__ kk1, const float* __restrict__ bb1,
    const float* __restrict__ kk2, const float* __restrict__ bb2,
    const float* __restrict__ kk3, const float* __restrict__ bb3,
    const float* __restrict__ w3, const float* __restrict__ w4,
    const float* __restrict__ cb4, const int* __restrict__ rec,
    float* __restrict__ s_out)
{
    __shared__ unsigned short Zs[128 * 136];   // Z, later H1 (bf16), rows padded to 136
    __shared__ float H2f[128 * 36];            // H2 fp32, rows padded to 36
    int bid = blockIdx.x, t = threadIdx.x;
    int bj = bid / 100, tile = bid % 100;
    int b = bj >> 2, j = bj & 3;
    int r0 = rec[0], r1 = rec[1], r2 = rec[2];
    int rb = (b == 0) ? r0 : ((b == 1) ? r1 : r2);
    if (j >= rb) return;
    int pix0 = tile * 128;

    // ---- stage Z (128 pix x 128 c bf16): cols 0-63 nbr, 64-127 ego ----
    const uint4* srcN = (const uint4*)(nbr_t + ((size_t)bj * HW + pix0) * 64);
    const uint4* srcE = (const uint4*)(ego_t + ((size_t)b * HW + pix0) * 64);
    #pragma unroll
    for (int i = 0; i < 4; ++i) {
        int u = i * 256 + t, p = u >> 3, cu = u & 7;
        *(uint4*)&Zs[p * 136 + cu * 8]      = srcN[u];
        *(uint4*)&Zs[p * 136 + 64 + cu * 8] = srcE[u];
    }
    __syncthreads();

    int lane = t & 63, wave = t >> 6;
    int r16 = lane & 15, q = lane >> 4;
    int wbase = wave * 32;
    const f32x4 z4 = {0.f, 0.f, 0.f, 0.f};

    // ---- layer 1: 128 -> 128 ----
    f32x4 acc[2][8];
    #pragma unroll
    for (int mt = 0; mt < 2; ++mt)
        #pragma unroll
        for (int nt = 0; nt < 8; ++nt) acc[mt][nt] = z4;

    #pragma unroll
    for (int ks = 0; ks < 4; ++ks) {
        int kcol = ks * 32 + q * 8;
        bf16x8 a0 = *(const bf16x8*)&Zs[(wbase + r16) * 136 + kcol];
        bf16x8 a1 = *(const bf16x8*)&Zs[(wbase + 16 + r16) * 136 + kcol];
        #pragma unroll
        for (int nt = 0; nt < 8; ++nt) {
            bf16x8 bf = *(const bf16x8*)(w1T + (nt * 16 + r16) * 128 + kcol);
            acc[0][nt] = __builtin_amdgcn_mfma_f32_16x16x32_bf16(a0, bf, acc[0][nt], 0, 0, 0);
            acc[1][nt] = __builtin_amdgcn_mfma_f32_16x16x32_bf16(a1, bf, acc[1][nt], 0, 0, 0);
        }
    }
    // BN1 + relu -> H1 bf16 back into Zs (each wave's 32-row slab is private)
    #pragma unroll
    for (int nt = 0; nt < 8; ++nt) {
        int o = nt * 16 + r16;
        float kv = kk1[o], bv = bb1[o];
        #pragma unroll
        for (int mt = 0; mt < 2; ++mt) {
            #pragma unroll
            for (int r = 0; r < 4; ++r) {
                float h = fmaxf(fmaf(acc[mt][nt][r], kv, bv), 0.f);
                int row = wbase + mt * 16 + q * 4 + r;
                Zs[row * 136 + o] = f2bf(h);
            }
        }
    }

    // ---- layer 2: 128 -> 32 ----
    f32x4 acc2[2][2];
    acc2[0][0] = z4; acc2[0][1] = z4; acc2[1][0] = z4; acc2[1][1] = z4;
    #pragma unroll
    for (int ks = 0; ks < 4; ++ks) {
        int kcol = ks * 32 + q * 8;
        bf16x8 a0 = *(const bf16x8*)&Zs[(wbase + r16) * 136 + kcol];
        bf16x8 a1 = *(const bf16x8*)&Zs[(wbase + 16 + r16) * 136 + kcol];
        #pragma unroll
        for (int nt = 0; nt < 2; ++nt) {
            bf16x8 bf = *(const bf16x8*)(w2T + (nt * 16 + r16) * 128 + kcol);
            acc2[0][nt] = __builtin_amdgcn_mfma_f32_16x16x32_bf16(a0, bf, acc2[0][nt], 0, 0, 0);
            acc2[1][nt] = __builtin_amdgcn_mfma_f32_16x16x32_bf16(a1, bf, acc2[1][nt], 0, 0, 0);
        }
    }
    #pragma unroll
    for (int nt = 0; nt < 2; ++nt) {
        int o2 = nt * 16 + r16;
        float kv = kk2[o2], bv = bb2[o2];
        #pragma unroll
        for (int mt = 0; mt < 2; ++mt) {
            #pragma unroll
            for (int r = 0; r < 4; ++r) {
                float h = fmaxf(fmaf(acc2[mt][nt][r], kv, bv), 0.f);
                int row = wbase + mt * 16 + q * 4 + r;
                H2f[row * 36 + o2] = h;
            }
        }
    }
    __syncthreads();

    // ---- layers 3-4: scalar (threads 0-127, one pixel each) ----
    if (t < 128) {
        float h2v[32];
        const float4* hp = (const float4*)&H2f[t * 36];
        #pragma unroll
        for (int qq = 0; qq < 8; ++qq) {
            float4 v = hp[qq];
            h2v[qq * 4 + 0] = v.x; h2v[qq * 4 + 1] = v.y;
            h2v[qq * 4 + 2] = v.z; h2v[qq * 4 + 3] = v.w;
        }
        float a3[8];
        #pragma unroll
        for (int o = 0; o < 8; ++o) a3[o] = 0.f;
        #pragma unroll
        for (int c = 0; c < 32; ++c) {
            #pragma unroll
            for (int o = 0; o < 8; ++o) a3[o] = fmaf(h2v[c], w3[c * 8 + o], a3[o]);
        }
        float s = cb4[0];
        #pragma unroll
        for (int o = 0; o < 8; ++o) {
            float h = fmaxf(fmaf(a3[o], kk3[o], bb3[o]), 0.f);
            s = fmaf(h, w4[o], s);
        }
        s = fmaxf(s, 0.f);
        s_out[(size_t)bj * HW + pix0 + t] = s;
    }
}

// ---------------- fuse: softmax over j + weighted sum + output MLP ----------------
// grid: 3 b x 200 tiles of 64 pixels; 256 threads

__global__ __launch_bounds__(256) void k_fuse(
    const unsigned short* __restrict__ nbr_t, const float* __restrict__ s_in,
    const float* __restrict__ com_in, const float* __restrict__ mlp_w,
    const float* __restrict__ mlp_b, float* __restrict__ out)
{
    __shared__ float s_s[256], com_s[256], wgt_s[256];
    __shared__ float updT[64 * 66];   // [c][pix], pix-padded rows
    __shared__ float w_s[64 * 64];    // mlp_w [c][d]
    int bid = blockIdx.x, t = threadIdx.x;
    int b = bid / 200, tile = bid % 200, pix0 = tile * 64;
    int p = t & 63, cg = t >> 6;

    {
        int jj = t >> 6;
        size_t g = ((size_t)(b * 4 + jj)) * HW + pix0 + (t & 63);
        s_s[t] = s_in[g];
        com_s[t] = com_in[g];
    }
    #pragma unroll
    for (int i = 0; i < 16; ++i) w_s[i * 256 + t] = mlp_w[i * 256 + t];
    __syncthreads();

    if (t < 64) {
        float sj[LL], cj[LL];
        #pragma unroll
        for (int j2 = 0; j2 < LL; ++j2) {
            cj[j2] = com_s[j2 * 64 + t];
            float sv = s_s[j2 * 64 + t];
            sj[j2] = (cj[j2] == 0.f) ? NEGf : sv;
        }
        float m = fmaxf(fmaxf(sj[0], sj[1]), fmaxf(sj[2], sj[3]));
        float e[LL], sum = 0.f;
        #pragma unroll
        for (int j2 = 0; j2 < LL; ++j2) { e[j2] = __expf(sj[j2] - m); sum += e[j2]; }
        float inv = 1.f / sum;
        #pragma unroll
        for (int j2 = 0; j2 < LL; ++j2) wgt_s[j2 * 64 + t] = e[j2] * inv * cj[j2];
    }
    __syncthreads();

    // phase 2: upd for 16 channels per thread, write transposed
    {
        float upd[16];
        #pragma unroll
        for (int i = 0; i < 16; ++i) upd[i] = 0.f;
        #pragma unroll
        for (int jj = 0; jj < LL; ++jj) {
            float wj = wgt_s[jj * 64 + p];
            const unsigned short* nr =
                nbr_t + ((size_t)(b * 4 + jj) * HW + pix0 + p) * 64 + cg * 16;
            uint4 v0 = *(const uint4*)nr;
            uint4 v1 = *(const uint4*)(nr + 8);
            unsigned int uu[8] = {v0.x, v0.y, v0.z, v0.w, v1.x, v1.y, v1.z, v1.w};
            #pragma unroll
            for (int k = 0; k < 8; ++k) {
                float lo = __uint_as_float(uu[k] << 16);
                float hi = __uint_as_float(uu[k] & 0xffff0000u);
                upd[k * 2 + 0] = fmaf(wj, lo, upd[k * 2 + 0]);
                upd[k * 2 + 1] = fmaf(wj, hi, upd[k * 2 + 1]);
            }
        }
        #pragma unroll
        for (int i = 0; i < 16; ++i) updT[(cg * 16 + i) * 66 + p] = upd[i];
    }
    __syncthreads();

    // phase 3: out[d] for 16 d per thread
    {
        int d0 = cg * 16;
        float acc[16];
        #pragma unroll
        for (int dd = 0; dd < 16; ++dd) acc[dd] = mlp_b[d0 + dd];
        #pragma unroll 4
        for (int c = 0; c < 64; ++c) {
            float u = updT[c * 66 + p];
            const float4* wp = (const float4*)&w_s[c * 64 + d0];
            float4 w0 = wp[0], w1v = wp[1], w2v = wp[2], w3v = wp[3];
            acc[0]  = fmaf(u, w0.x,  acc[0]);  acc[1]  = fmaf(u, w0.y,  acc[1]);
            acc[2]  = fmaf(u, w0.z,  acc[2]);  acc[3]  = fmaf(u, w0.w,  acc[3]);
            acc[4]  = fmaf(u, w1v.x, acc[4]);  acc[5]  = fmaf(u, w1v.y, acc[5]);
            acc[6]  = fmaf(u, w1v.z, acc[6]);  acc[7]  = fmaf(u, w1v.w, acc[7]);
            acc[8]  = fmaf(u, w2v.x, acc[8]);  acc[9]  = fmaf(u, w2v.y, acc[9]);
            acc[10] = fmaf(u, w2v.z, acc[10]); acc[11] = fmaf(u, w2v.w, acc[11]);
            acc[12] = fmaf(u, w3v.x, acc[12]); acc[13] = fmaf(u, w3v.y, acc[13]);
            acc[14] = fmaf(u, w3v.z, acc[14]); acc[15] = fmaf(u, w3v.w, acc[15]);
        }
        #pragma unroll
        for (int dd = 0; dd < 16; ++dd)
            out[((size_t)(b * CC) + d0 + dd) * HW + pix0 + p] = acc[dd];
    }
}

// ---------------- launch ----------------

extern "C" void kernel_launch(void* const* d_in, const int* in_sizes, int n_in,
                              void* d_out, int out_size, void* d_ws, size_t ws_size,
                              hipStream_t stream)
{
    const float* x    = (const float*)d_in[0];
    const float* mask = (const float*)d_in[1];
    const int*   rec  = (const int*)  d_in[2];
    const float* ptm  = (const float*)d_in[3];
    const float* w1   = (const float*)d_in[4];
    const float* cb1  = (const float*)d_in[5];
    const float* g1   = (const float*)d_in[6];
    const float* be1  = (const float*)d_in[7];
    const float* rm1  = (const float*)d_in[8];
    const float* rv1  = (const float*)d_in[9];
    const float* w2   = (const float*)d_in[10];
    const float* cb2  = (const float*)d_in[11];
    const float* g2   = (const float*)d_in[12];
    const float* be2  = (const float*)d_in[13];
    const float* rm2  = (const float*)d_in[14];
    const float* rv2  = (const float*)d_in[15];
    const float* w3   = (const float*)d_in[16];
    const float* cb3  = (const float*)d_in[17];
    const float* g3   = (const float*)d_in[18];
    const float* be3  = (const float*)d_in[19];
    const float* rm3  = (const float*)d_in[20];
    const float* rv3  = (const float*)d_in[21];
    const float* w4   = (const float*)d_in[22];
    const float* cb4  = (const float*)d_in[23];
    const float* mlpw = (const float*)d_in[24];
    const float* mlpb = (const float*)d_in[25];
    float* out = (float*)d_out;

    // workspace layout (bytes, 16B aligned)
    unsigned short* nbr_t = (unsigned short*)d_ws;              // 12*HW*64 ushort
    unsigned short* ego_t = nbr_t + (size_t)12 * HW * 64;      // 3*HW*64 ushort
    float* s_ws   = (float*)(ego_t + (size_t)3 * HW * 64);
    float* com_ws = s_ws + (size_t)12 * HW;
    unsigned short* w1T = (unsigned short*)(com_ws + (size_t)12 * HW);
    unsigned short* w2T = w1T + 16384;
    float* kk1 = (float*)(w2T + 4096);
    float* bb1 = kk1 + 128;
    float* kk2 = bb1 + 128;
    float* bb2 = kk2 + 32;
    float* kk3 = bb2 + 32;
    float* bb3 = kk3 + 8;

    k_prep<<<dim3(81), dim3(256), 0, stream>>>(
        w1, w2, cb1, g1, be1, rm1, rv1, cb2, g2, be2, rm2, rv2,
        cb3, g3, be3, rm3, rv3, w1T, w2T, kk1, bb1, kk2, bb2, kk3, bb3);

    k_warp<<<dim3(3000), dim3(256), 0, stream>>>(
        x, mask, rec, ptm, nbr_t, ego_t, com_ws);

    k_score<<<dim3(1200), dim3(256), 0, stream>>>(
        nbr_t, ego_t, w1T, w2T, kk1, bb1, kk2, bb2, kk3, bb3,
        w3, w4, cb4, rec, s_ws);

    k_fuse<<<dim3(600), dim3(256), 0, stream>>>(
        nbr_t, s_ws, com_ws, mlpw, mlpb, out);
}

// Round 3
// 177.132 us; speedup vs baseline: 2.3016x; 1.0229x over previous
//
#include <hip/hip_runtime.h>
#include <math.h>

#define CC 64
#define HH 80
#define WW 160
#define BB 3
#define LL 4
#define HW (HH * WW)          // 12800
#define EPSf 1e-5f
#define NEGf -1e30f

typedef __attribute__((ext_vector_type(8))) short bf16x8;
typedef __attribute__((ext_vector_type(4))) float f32x4;

union BU { unsigned short s[8]; bf16x8 v; };

__device__ __forceinline__ unsigned short f2bf(float f) {
    unsigned int u = __float_as_uint(f);
    u = u + 0x7fffu + ((u >> 16) & 1u);      // RNE
    return (unsigned short)(u >> 16);
}
__device__ __forceinline__ float b2f(unsigned short h) {
    return __uint_as_float(((unsigned int)h) << 16);
}

__device__ __forceinline__ void src_xy(const float* __restrict__ th, int pix,
                                       float& px, float& py) {
    int w = pix % WW, h = pix / WW;
    float gx = -1.f + 2.f * (float)w / (float)(WW - 1);
    float gy = -1.f + 2.f * (float)h / (float)(HH - 1);
    float sx = th[0] * gx + th[1] * gy + th[2];
    float sy = th[3] * gx + th[4] * gy + th[5];
    px = (sx + 1.f) * (float)(WW - 1) * 0.5f;
    py = (sy + 1.f) * (float)(HH - 1) * 0.5f;
}

struct Tap { int a00, a01, a10, a11; float w00, w01, w10, w11; };

__device__ __forceinline__ Tap mk_tap(float px, float py) {
    Tap tp;
    float x0f = floorf(px), y0f = floorf(py);
    float wx = px - x0f, wy = py - y0f;
    int x0 = (int)x0f, y0 = (int)y0f, x1 = x0 + 1, y1 = y0 + 1;
    float bx0 = (x0 >= 0 && x0 < WW) ? 1.f : 0.f;
    float bx1 = (x1 >= 0 && x1 < WW) ? 1.f : 0.f;
    float by0 = (y0 >= 0 && y0 < HH) ? 1.f : 0.f;
    float by1 = (y1 >= 0 && y1 < HH) ? 1.f : 0.f;
    int xc0 = min(max(x0, 0), WW - 1), xc1 = min(max(x1, 0), WW - 1);
    int yc0 = min(max(y0, 0), HH - 1), yc1 = min(max(y1, 0), HH - 1);
    tp.w00 = (1.f - wx) * (1.f - wy) * bx0 * by0;
    tp.w01 = wx * (1.f - wy) * bx1 * by0;
    tp.w10 = (1.f - wx) * wy * bx0 * by1;
    tp.w11 = wx * wy * bx1 * by1;
    tp.a00 = yc0 * WW + xc0; tp.a01 = yc0 * WW + xc1;
    tp.a10 = yc1 * WW + xc0; tp.a11 = yc1 * WW + xc1;
    return tp;
}

// ---------------- prep: weight transpose+bf16, BN folding ----------------
// ws ushort layout: [0,16384) w1T[o][c]; [16384,20480) w2T[o2][o];
// [20480,24576) mwT[d][c]; then f32: kk1,bb1(128) kk2,bb2(32) kk3,bb3(8)

__global__ __launch_bounds__(256) void k_prep(
    const float* __restrict__ w1, const float* __restrict__ w2,
    const float* __restrict__ mlpw,
    const float* __restrict__ cb1, const float* __restrict__ g1,
    const float* __restrict__ be1, const float* __restrict__ rm1, const float* __restrict__ rv1,
    const float* __restrict__ cb2, const float* __restrict__ g2,
    const float* __restrict__ be2, const float* __restrict__ rm2, const float* __restrict__ rv2,
    const float* __restrict__ cb3, const float* __restrict__ g3,
    const float* __restrict__ be3, const float* __restrict__ rm3, const float* __restrict__ rv3,
    unsigned short* __restrict__ w1T, unsigned short* __restrict__ w2T,
    unsigned short* __restrict__ mwT,
    float* __restrict__ kk1, float* __restrict__ bb1,
    float* __restrict__ kk2, float* __restrict__ bb2,
    float* __restrict__ kk3, float* __restrict__ bb3)
{
    int idx = blockIdx.x * 256 + threadIdx.x;
    if (idx < 16384) {                       // w1T[o][c] = w1[c][o]
        int o = idx >> 7, c = idx & 127;
        w1T[idx] = f2bf(w1[c * 128 + o]);
    } else if (idx < 20480) {                // w2T[o2][o] = w2[o][o2]
        int i = idx - 16384;
        int o2 = i >> 7, o = i & 127;
        w2T[i] = f2bf(w2[o * 32 + o2]);
    } else if (idx < 24576) {                // mwT[d][c] = mlpw[c][d]
        int i = idx - 20480;
        int d = i >> 6, c = i & 63;
        mwT[i] = f2bf(mlpw[c * 64 + d]);
    } else if (idx < 24704) {
        int o = idx - 24576;
        float k = g1[o] * rsqrtf(rv1[o] + EPSf);
        kk1[o] = k; bb1[o] = fmaf(cb1[o] - rm1[o], k, be1[o]);
    } else if (idx < 24736) {
        int o = idx - 24704;
        float k = g2[o] * rsqrtf(rv2[o] + EPSf);
        kk2[o] = k; bb2[o] = fmaf(cb2[o] - rm2[o], k, be2[o]);
    } else if (idx < 24744) {
        int o = idx - 24736;
        float k = g3[o] * rsqrtf(rv3[o] + EPSf);
        kk3[o] = k; bb3[o] = fmaf(cb3[o] - rm3[o], k, be3[o]);
    }
}

// ---------------- fused: warp + score MLP + softmax + fuse + out MLP ----------------
// grid: 3 b x 200 tiles of 64 pixels; 256 threads = 4 waves.
// thread (wave,q,r16): pixel p = wave*16+r16, channels ks*32+q*8+i (A-frag layout)

__global__ __launch_bounds__(256, 2) void k_fused(
    const float* __restrict__ x, const float* __restrict__ mask,
    const int* __restrict__ rec, const float* __restrict__ ptm,
    const unsigned short* __restrict__ w1T, const unsigned short* __restrict__ w2T,
    const unsigned short* __restrict__ mwT,
    const float* __restrict__ kk1, const float* __restrict__ bb1,
    const float* __restrict__ kk2, const float* __restrict__ bb2,
    const float* __restrict__ kk3, const float* __restrict__ bb3,
    const float* __restrict__ w3, const float* __restrict__ w4,
    const float* __restrict__ cb4, const float* __restrict__ mlp_b,
    float* __restrict__ out)
{
    __shared__ unsigned short H1s[64 * 136];  // H1 bf16; later reused as outT f32 [64][65]
    __shared__ float H2f[64 * 36];
    __shared__ float s_s[4 * 64];
    __shared__ float com_s[4 * 64];

    int t = threadIdx.x;
    int b = blockIdx.x / 200, tile = blockIdx.x % 200;
    int pix0 = tile * 64;
    int wave = t >> 6, lane = t & 63, q = lane >> 4, r16 = lane & 15;
    int p = wave * 16 + r16;            // pixel within tile
    int pix = pix0 + p;

    int r0 = rec[0], r1 = rec[1], r2 = rec[2];
    int rb = (b == 0) ? r0 : ((b == 1) ? r1 : r2);
    int off = (b >= 1 ? r0 : 0) + (b >= 2 ? r1 : 0);

    // hoisted per-lane BN consts
    float kv1[8], bv1[8];
    #pragma unroll
    for (int nt = 0; nt < 8; ++nt) { int o = nt * 16 + r16; kv1[nt] = kk1[o]; bv1[nt] = bb1[o]; }
    float kv2[2], bv2[2];
    #pragma unroll
    for (int nt = 0; nt < 2; ++nt) { int o = nt * 16 + r16; kv2[nt] = kk2[o]; bv2[nt] = bb2[o]; }

    // ego A-fragments (channels q*8+i and 32+q*8+i at pixel p) — reused all j
    bf16x8 e0, e1;
    {
        BU u0, u1;
        const float* xe = x + (size_t)off * CC * HW + pix;
        #pragma unroll
        for (int i = 0; i < 8; ++i) {
            u0.s[i] = f2bf(xe[(size_t)(q * 8 + i) * HW]);
            u1.s[i] = f2bf(xe[(size_t)(32 + q * 8 + i) * HW]);
        }
        e0 = u0.v; e1 = u1.v;
    }

    const f32x4 z4 = {0.f, 0.f, 0.f, 0.f};
    bf16x8 nbrA[8];                     // [j][ksgroup] nbr channels, kept in regs

    #pragma unroll
    for (int j = 0; j < 4; ++j) {
        bf16x8 a0 = {0,0,0,0,0,0,0,0}, a1 = {0,0,0,0,0,0,0,0};
        bool valid = j < rb;            // block-uniform
        if (valid) {
            // ---- gather nbr channels for pixel p ----
            const float* th = ptm + ((size_t)(b * 4 + j) * 4) * 6;  // ptm[b][j][0]
            float px, py; src_xy(th, pix, px, py);
            Tap tp = mk_tap(px, py);
            const float* feat = x + (size_t)(off + j) * CC * HW;
            BU u0, u1;
            #pragma unroll
            for (int i = 0; i < 8; ++i) {
                const float* f0 = feat + (size_t)(q * 8 + i) * HW;
                float v0 = tp.w00 * f0[tp.a00] + tp.w01 * f0[tp.a01]
                         + tp.w10 * f0[tp.a10] + tp.w11 * f0[tp.a11];
                u0.s[i] = f2bf(v0);
                const float* f1 = feat + (size_t)(32 + q * 8 + i) * HW;
                float v1 = tp.w00 * f1[tp.a00] + tp.w01 * f1[tp.a01]
                         + tp.w10 * f1[tp.a10] + tp.w11 * f1[tp.a11];
                u1.s[i] = f2bf(v1);
            }
            a0 = u0.v; a1 = u1.v;

            // ---- layer 1: [nbr;ego](128) -> 128, A-frags in regs ----
            f32x4 acc1[8];
            #pragma unroll
            for (int nt = 0; nt < 8; ++nt) acc1[nt] = z4;
            #pragma unroll
            for (int ks = 0; ks < 4; ++ks) {
                bf16x8 A = (ks == 0) ? a0 : (ks == 1) ? a1 : (ks == 2) ? e0 : e1;
                int kcol = ks * 32 + q * 8;
                #pragma unroll
                for (int nt = 0; nt < 8; ++nt) {
                    bf16x8 bf = *(const bf16x8*)(w1T + (size_t)(nt * 16 + r16) * 128 + kcol);
                    acc1[nt] = __builtin_amdgcn_mfma_f32_16x16x32_bf16(A, bf, acc1[nt], 0, 0, 0);
                }
            }
            // BN1+relu -> H1s (C-layout rows are this wave's own pixel slab)
            #pragma unroll
            for (int nt = 0; nt < 8; ++nt) {
                #pragma unroll
                for (int r = 0; r < 4; ++r) {
                    float h = fmaxf(fmaf(acc1[nt][r], kv1[nt], bv1[nt]), 0.f);
                    H1s[(wave * 16 + q * 4 + r) * 136 + nt * 16 + r16] = f2bf(h);
                }
            }
            // ---- layer 2: 128 -> 32 (A from H1s, same-wave rows, no barrier) ----
            f32x4 acc2[2]; acc2[0] = z4; acc2[1] = z4;
            #pragma unroll
            for (int ks = 0; ks < 4; ++ks) {
                int kcol = ks * 32 + q * 8;
                bf16x8 A = *(const bf16x8*)&H1s[(wave * 16 + r16) * 136 + kcol];
                #pragma unroll
                for (int nt = 0; nt < 2; ++nt) {
                    bf16x8 bf = *(const bf16x8*)(w2T + (size_t)(nt * 16 + r16) * 128 + kcol);
                    acc2[nt] = __builtin_amdgcn_mfma_f32_16x16x32_bf16(A, bf, acc2[nt], 0, 0, 0);
                }
            }
            #pragma unroll
            for (int nt = 0; nt < 2; ++nt) {
                #pragma unroll
                for (int r = 0; r < 4; ++r) {
                    float h = fmaxf(fmaf(acc2[nt][r], kv2[nt], bv2[nt]), 0.f);
                    H2f[(wave * 16 + q * 4 + r) * 36 + nt * 16 + r16] = h;
                }
            }
        }
        __syncthreads();
        // ---- layers 3-4 + mask warp: wave 0, one pixel per thread ----
        if (t < 64) {
            if (valid) {
                const float* th = ptm + ((size_t)(b * 4 + j) * 4) * 6;
                float px, py; src_xy(th, pix0 + t, px, py);
                Tap tp = mk_tap(px, py);
                const float* mk = mask + (size_t)(b * 4 + j) * HW;
                float wm = tp.w00 * mk[tp.a00] + tp.w01 * mk[tp.a01]
                         + tp.w10 * mk[tp.a10] + tp.w11 * mk[tp.a11];
                float a3[8];
                #pragma unroll
                for (int o = 0; o < 8; ++o) a3[o] = 0.f;
                #pragma unroll 4
                for (int c = 0; c < 32; ++c) {
                    float hv = H2f[t * 36 + c];
                    #pragma unroll
                    for (int o = 0; o < 8; ++o) a3[o] = fmaf(hv, w3[c * 8 + o], a3[o]);
                }
                float s = cb4[0];
                #pragma unroll
                for (int o = 0; o < 8; ++o) {
                    float h = fmaxf(fmaf(a3[o], kk3[o], bb3[o]), 0.f);
                    s = fmaf(h, w4[o], s);
                }
                s = fmaxf(s, 0.f);
                s_s[j * 64 + t] = (wm == 0.f) ? NEGf : s;
                com_s[j * 64 + t] = wm;
            } else {
                s_s[j * 64 + t] = NEGf;
                com_s[j * 64 + t] = 0.f;
            }
        }
        __syncthreads();
        nbrA[j * 2 + 0] = a0;
        nbrA[j * 2 + 1] = a1;
    }

    // ---- softmax over j + weighted nbr sum (all in regs) ----
    float sj[4], cj[4];
    #pragma unroll
    for (int j = 0; j < 4; ++j) { sj[j] = s_s[j * 64 + p]; cj[j] = com_s[j * 64 + p]; }
    float m = fmaxf(fmaxf(sj[0], sj[1]), fmaxf(sj[2], sj[3]));
    float e[4], sum = 0.f;
    #pragma unroll
    for (int j = 0; j < 4; ++j) { e[j] = __expf(sj[j] - m); sum += e[j]; }
    float inv = 1.f / sum;
    float wgt[4];
    #pragma unroll
    for (int j = 0; j < 4; ++j) wgt[j] = e[j] * inv * cj[j];

    float u0f[8], u1f[8];
    #pragma unroll
    for (int i = 0; i < 8; ++i) { u0f[i] = 0.f; u1f[i] = 0.f; }
    #pragma unroll
    for (int j = 0; j < 4; ++j) {
        float wj = wgt[j];
        #pragma unroll
        for (int i = 0; i < 8; ++i) {
            u0f[i] = fmaf(wj, b2f((unsigned short)nbrA[j * 2 + 0][i]), u0f[i]);
            u1f[i] = fmaf(wj, b2f((unsigned short)nbrA[j * 2 + 1][i]), u1f[i]);
        }
    }
    BU p0, p1;
    #pragma unroll
    for (int i = 0; i < 8; ++i) { p0.s[i] = f2bf(u0f[i]); p1.s[i] = f2bf(u1f[i]); }

    // ---- output MLP: upd(64) x mlpw(64x64) via MFMA ----
    f32x4 acc3[4];
    #pragma unroll
    for (int nt = 0; nt < 4; ++nt) acc3[nt] = z4;
    #pragma unroll
    for (int ks = 0; ks < 2; ++ks) {
        bf16x8 A = ks ? p1.v : p0.v;
        int kcol = ks * 32 + q * 8;
        #pragma unroll
        for (int nt = 0; nt < 4; ++nt) {
            bf16x8 bf = *(const bf16x8*)(mwT + (size_t)(nt * 16 + r16) * 64 + kcol);
            acc3[nt] = __builtin_amdgcn_mfma_f32_16x16x32_bf16(A, bf, acc3[nt], 0, 0, 0);
        }
    }

    // transpose via LDS (overlay on H1s; all H1s reads completed before last barrier)
    float* outT = (float*)H1s;          // [64 d][65 pix]
    #pragma unroll
    for (int nt = 0; nt < 4; ++nt) {
        int d = nt * 16 + r16;
        float mb = mlp_b[d];
        #pragma unroll
        for (int r = 0; r < 4; ++r)
            outT[d * 65 + wave * 16 + q * 4 + r] = acc3[nt][r] + mb;
    }
    __syncthreads();
    {
        int p2 = t & 63, dg = t >> 6;
        #pragma unroll
        for (int i = 0; i < 16; ++i) {
            int d = dg * 16 + i;
            out[((size_t)(b * CC + d)) * HW + pix0 + p2] = outT[d * 65 + p2];
        }
    }
}

// ---------------- launch ----------------

extern "C" void kernel_launch(void* const* d_in, const int* in_sizes, int n_in,
                              void* d_out, int out_size, void* d_ws, size_t ws_size,
                              hipStream_t stream)
{
    const float* x    = (const float*)d_in[0];
    const float* mask = (const float*)d_in[1];
    const int*   rec  = (const int*)  d_in[2];
    const float* ptm  = (const float*)d_in[3];
    const float* w1   = (const float*)d_in[4];
    const float* cb1  = (const float*)d_in[5];
    const float* g1   = (const float*)d_in[6];
    const float* be1  = (const float*)d_in[7];
    const float* rm1  = (const float*)d_in[8];
    const float* rv1  = (const float*)d_in[9];
    const float* w2   = (const float*)d_in[10];
    const float* cb2  = (const float*)d_in[11];
    const float* g2   = (const float*)d_in[12];
    const float* be2  = (const float*)d_in[13];
    const float* rm2  = (const float*)d_in[14];
    const float* rv2  = (const float*)d_in[15];
    const float* w3   = (const float*)d_in[16];
    const float* cb3  = (const float*)d_in[17];
    const float* g3   = (const float*)d_in[18];
    const float* be3  = (const float*)d_in[19];
    const float* rm3  = (const float*)d_in[20];
    const float* rv3  = (const float*)d_in[21];
    const float* w4   = (const float*)d_in[22];
    const float* cb4  = (const float*)d_in[23];
    const float* mlpw = (const float*)d_in[24];
    const float* mlpb = (const float*)d_in[25];
    float* out = (float*)d_out;

    unsigned short* w1T = (unsigned short*)d_ws;   // 16384
    unsigned short* w2T = w1T + 16384;             // 4096
    unsigned short* mwT = w2T + 4096;              // 4096
    float* kk1 = (float*)(mwT + 4096);
    float* bb1 = kk1 + 128;
    float* kk2 = bb1 + 128;
    float* bb2 = kk2 + 32;
    float* kk3 = bb2 + 32;
    float* bb3 = kk3 + 8;

    k_prep<<<dim3(97), dim3(256), 0, stream>>>(
        w1, w2, mlpw, cb1, g1, be1, rm1, rv1, cb2, g2, be2, rm2, rv2,
        cb3, g3, be3, rm3, rv3, w1T, w2T, mwT, kk1, bb1, kk2, bb2, kk3, bb3);

    k_fused<<<dim3(600), dim3(256), 0, stream>>>(
        x, mask, rec, ptm, w1T, w2T, mwT,
        kk1, bb1, kk2, bb2, kk3, bb3,
        w3, w4, cb4, mlpb, out);
}